// Round 1
// baseline (63.732 us; speedup 1.0000x reference)
//
#include <hip/hip_runtime.h>

// Fused: reshape -> 1x1 mix (w1) -> double-unfold conv (w0) -> reshape -> roll(+1, H)
//
// Math per output (c = l*4 + p, h, n), with o = (h-1) mod 56:
//   t4[p,j,n] = sum_q x[2q+j, o, n] * w1[p,q]              (j in [0,2), q in [0,64))
//   out[c,h,n] = sum_{j,k,i} w0[l,j,i,k] * t4[p,j, n+k+i-2]
//                gated on (0 <= n+k-1 < 56) AND (0 <= n+k+i-2 < 56)
// The second gate is realized by a zero pad of 1 on each side of the t4 row;
// the first gate is an explicit predicate per k (two-stage-unfold semantics:
// e.g. n=0,k=0,i=2 hits a valid t4 index but must still be zero).

__global__ __launch_bounds__(256) void fused_shift_unfold_kernel(
    const float* __restrict__ x,    // [128,56,56]
    const float* __restrict__ w0,   // [32,2,3,3]
    const float* __restrict__ w1,   // [4,64]
    float* __restrict__ out)        // [128,56,56]
{
    __shared__ float s_x[128 * 56];   // input row-slab: 28672 B
    __shared__ float s_t4[8][58];     // t4 rows (p*2+j), pad 1 each side
    __shared__ float s_w0[144];       // this block's 8 l-values: 8*2*3*3
    __shared__ float s_w1[256];       // [4][64]

    const int tid = threadIdx.x;
    const int h   = blockIdx.x;          // output H row
    const int by  = blockIdx.y;          // channel quarter: c in [by*32, by*32+32)
    const int o   = (h + 55) % 56;       // source H row (roll by +1)

    // ---- stage weights ----
    s_w1[tid] = w1[tid];                              // 256 threads, 256 elems
    if (tid < 144) s_w0[tid] = w0[by * 144 + tid];    // l in [by*8, by*8+8)
    if (tid < 8) { s_t4[tid][0] = 0.f; s_t4[tid][57] = 0.f; }

    // ---- stage x row-slab (coalesced 56-float segments) ----
    const float* xrow = x + o * 56;
    for (int t = tid; t < 128 * 56; t += 256) {
        int ch = t / 56;
        int n  = t - ch * 56;
        s_x[t] = xrow[ch * 3136 + n];
    }
    __syncthreads();

    // ---- t4: 448 values = 8 (p,j) rows x 56 ----
    for (int v = tid; v < 448; v += 256) {
        int p  = v / 112;
        int r  = v - p * 112;
        int jg = r / 56;
        int n  = r - jg * 56;
        const float* wrow = &s_w1[p * 64];
        const float* xs   = &s_x[jg * 56 + n];   // stride 112 over q (ch = 2q+jg)
        float acc = 0.f;
        #pragma unroll
        for (int q = 0; q < 64; ++q)
            acc += wrow[q] * xs[q * 112];
        s_t4[p * 2 + jg][n + 1] = acc;
    }
    __syncthreads();

    // ---- conv + store: 32 channels x 56 width per block, 7 outputs/thread ----
    float* orow = out + h * 56;
    for (int v = tid; v < 32 * 56; v += 256) {
        int cl = v / 56;                  // local channel [0,32)
        int n  = v - cl * 56;
        int c  = by * 32 + cl;            // global channel = l*4 + p
        int ll = cl >> 2;                 // local l (w0 staged per-block)
        int p  = c & 3;
        float acc = 0.f;
        #pragma unroll
        for (int jg = 0; jg < 2; ++jg) {
            const float* row = s_t4[p * 2 + jg];      // row[m+1] = t4[.., m]
            const float* wj  = &s_w0[(ll * 2 + jg) * 9];  // wj[i*3+k]
            #pragma unroll
            for (int k = 0; k < 3; ++k) {
                int m = n + k - 1;                    // first-unfold position
                if ((unsigned)m < 56u) {              // outer gate
                    acc += wj[0 * 3 + k] * row[m    ];   // i=0 -> t4[m-1]
                    acc += wj[1 * 3 + k] * row[m + 1];   // i=1 -> t4[m]
                    acc += wj[2 * 3 + k] * row[m + 2];   // i=2 -> t4[m+1]
                }
            }
        }
        orow[c * 3136 + n] = acc;
    }
}

extern "C" void kernel_launch(void* const* d_in, const int* in_sizes, int n_in,
                              void* d_out, int out_size, void* d_ws, size_t ws_size,
                              hipStream_t stream) {
    (void)in_sizes; (void)n_in; (void)out_size; (void)d_ws; (void)ws_size;
    const float* x  = (const float*)d_in[0];   // [1,128,56,56]
    const float* w0 = (const float*)d_in[1];   // [32,2,3,3]
    const float* w1 = (const float*)d_in[2];   // [4,64]
    float* out = (float*)d_out;                // [1,128,56,56]

    dim3 grid(56, 4);
    fused_shift_unfold_kernel<<<grid, 256, 0, stream>>>(x, w0, w1, out);
}

// Round 2
// 61.892 us; speedup vs baseline: 1.0297x; 1.0297x over previous
//
#include <hip/hip_runtime.h>

// Fused: reshape -> 1x1 mix (w1) -> double-unfold conv (w0) -> reshape -> roll(+1, H)
//
// Math per output (c = 4l + p, h, n), with o = (h-1) mod 56:
//   t4[p,j,n]  = sum_q x[2q+j, o, n] * w1[p,q]            (q in [0,64))
//   out[c,h,n] = sum_{j,k,i} w0[l,j,i,k] * t4[p,j, n+k+i-2]
//                gated on (0 <= n+k-1 < 56) AND (0 <= n+k+i-2 < 56)
// Second gate = zero pad 1 on each side of the t4 row; first gate = explicit
// predicate per k (two-stage-unfold semantics).
//
// Round 2: blockIdx.y = p (not channel quarter) -> zero t4 redundancy, t4 read
// directly from global (L2-resident x, coalesced, scalar w1), w0 staged by the
// otherwise-idle threads, single barrier.

__global__ __launch_bounds__(256) void fused_shift_unfold_kernel(
    const float* __restrict__ x,    // [128,56,56]
    const float* __restrict__ w0,   // [32,2,3,3]
    const float* __restrict__ w1,   // [4,64]
    float* __restrict__ out)        // [128,56,56]
{
    __shared__ float s_t4[2][58];    // t4 rows for this p, pad 1 each side
    __shared__ float s_w0[576];      // all 32 l: [l][j][i][k]

    const int tid = threadIdx.x;
    const int h   = blockIdx.x;          // output H row
    const int p   = blockIdx.y;          // p = c & 3
    const int o   = (h + 55) % 56;       // source H row (roll by +1)

    if (tid < 112) {
        // ---- t4: one value per thread, straight from global (L2-hot) ----
        const int j = (tid >= 56);
        const int n = tid - j * 56;
        const float* xp = x + j * 3136 + o * 56 + n;   // channel 2q+j -> +q*6272
        const float* wp = w1 + p * 64;                 // wave-uniform -> s_load
        float a0 = 0.f, a1 = 0.f, a2 = 0.f, a3 = 0.f;
        #pragma unroll
        for (int q = 0; q < 64; q += 4) {
            a0 += wp[q + 0] * xp[(q + 0) * 6272];
            a1 += wp[q + 1] * xp[(q + 1) * 6272];
            a2 += wp[q + 2] * xp[(q + 2) * 6272];
            a3 += wp[q + 3] * xp[(q + 3) * 6272];
        }
        s_t4[j][n + 1] = (a0 + a1) + (a2 + a3);
    } else {
        // ---- concurrently stage w0 (576 floats over 144 threads) + pads ----
        const int t = tid - 112;         // [0,144)
        #pragma unroll
        for (int r = 0; r < 4; ++r)
            s_w0[t * 4 + r] = w0[t * 4 + r];
        if (t < 4) s_t4[t >> 1][(t & 1) * 57] = 0.f;
    }
    __syncthreads();

    // ---- conv + store: 32 l-values x 56 width, 7 outputs/thread ----
    float* orow = out + h * 56;
    #pragma unroll
    for (int it = 0; it < 7; ++it) {
        const int v = tid + it * 256;    // [0,1792)
        const int l = v / 56;            // [0,32)
        const int n = v - l * 56;
        float acc = 0.f;
        #pragma unroll
        for (int j = 0; j < 2; ++j) {
            const float* row = s_t4[j];            // row[m+1] = t4[p,j,m]
            const float* wj  = &s_w0[(l * 2 + j) * 9];   // wj[i*3+k]
            #pragma unroll
            for (int k = 0; k < 3; ++k) {
                const int m = n + k - 1;           // first-unfold position
                if ((unsigned)m < 56u) {           // outer gate
                    acc += wj[0 + k] * row[m    ];     // i=0 -> t4[m-1]
                    acc += wj[3 + k] * row[m + 1];     // i=1 -> t4[m]
                    acc += wj[6 + k] * row[m + 2];     // i=2 -> t4[m+1]
                }
            }
        }
        orow[(l * 4 + p) * 3136 + n] = acc;        // c = 4l + p
    }
}

extern "C" void kernel_launch(void* const* d_in, const int* in_sizes, int n_in,
                              void* d_out, int out_size, void* d_ws, size_t ws_size,
                              hipStream_t stream) {
    (void)in_sizes; (void)n_in; (void)out_size; (void)d_ws; (void)ws_size;
    const float* x  = (const float*)d_in[0];   // [1,128,56,56]
    const float* w0 = (const float*)d_in[1];   // [32,2,3,3]
    const float* w1 = (const float*)d_in[2];   // [4,64]
    float* out = (float*)d_out;                // [1,128,56,56]

    dim3 grid(56, 4);
    fused_shift_unfold_kernel<<<grid, 256, 0, stream>>>(x, w0, w1, out);
}

// Round 3
// 59.365 us; speedup vs baseline: 1.0736x; 1.0426x over previous
//
#include <hip/hip_runtime.h>

// Fused: reshape -> 1x1 mix (w1) -> double-unfold conv (w0) -> reshape -> roll(+1, H)
//
// Math per output (c = 4l + p, h, n), with o = (h-1) mod 56:
//   t4[p,j,n]  = sum_q x[2q+j, o, n] * w1[p,q]            (q in [0,64))
//   out[c,h,n] = sum_{j,k,i} w0[l,j,i,k] * t4[p,j, n+k+i-2]
//                gated on (0 <= n+k-1 < 56) AND (0 <= n+k+i-2 < 56)
// i-gate: zero pad of 2 on each side of the t4 row (all taps unconditional ->
// full CSE of LDS reads). k-gate: branchless select of the per-k partial sum
// (two-stage-unfold semantics).
//
// Round 3: conv remapped to l=tid>>3, n=(tid&7)+8i (no divisions), w0 in 18
// registers loaded once, pad-2 rows for unconditional taps.

__global__ __launch_bounds__(256) void fused_shift_unfold_kernel(
    const float* __restrict__ x,    // [128,56,56]
    const float* __restrict__ w0,   // [32,2,3,3]
    const float* __restrict__ w1,   // [4,64]
    float* __restrict__ out)        // [128,56,56]
{
    __shared__ float s_t4[2][60];    // s_t4[j][n+2] = t4[p,j,n]; pad 2 each side
    __shared__ float s_w0[576];      // [l][j][i][k]

    const int tid = threadIdx.x;
    const int h   = blockIdx.x;           // output H row
    const int p   = blockIdx.y;           // p = c & 3
    const int o   = h ? h - 1 : 55;       // source H row (roll by +1)

    if (tid < 112) {
        // ---- t4: one value per thread, straight from global (L2-hot) ----
        const int j = (tid >= 56);
        const int n = tid - j * 56;
        const float* xp = x + j * 3136 + o * 56 + n;   // channel 2q+j -> +q*6272
        const float* wp = w1 + p * 64;                 // wave-uniform -> s_load
        float a0 = 0.f, a1 = 0.f, a2 = 0.f, a3 = 0.f;
        #pragma unroll
        for (int q = 0; q < 64; q += 4) {
            a0 += wp[q + 0] * xp[(q + 0) * 6272];
            a1 += wp[q + 1] * xp[(q + 1) * 6272];
            a2 += wp[q + 2] * xp[(q + 2) * 6272];
            a3 += wp[q + 3] * xp[(q + 3) * 6272];
        }
        s_t4[j][n + 2] = (a0 + a1) + (a2 + a3);
    } else {
        // ---- concurrently stage w0 (144 threads x float4) + zero pads ----
        const int t = tid - 112;          // [0,144)
        ((float4*)s_w0)[t] = ((const float4*)w0)[t];
        if (t < 8) {                      // pads: [j][0,1,58,59]
            const int j   = t & 1;
            const int q2  = t >> 1;       // 0..3
            s_t4[j][q2 < 2 ? q2 : q2 + 56] = 0.f;
        }
    }
    __syncthreads();

    // ---- conv + store: thread = (l, b); outputs n = b + 8i ----
    const int l = tid >> 3;               // [0,32)
    const int b = tid & 7;

    float wreg[2][9];                     // wreg[j][i*3+k]
    #pragma unroll
    for (int j = 0; j < 2; ++j)
        #pragma unroll
        for (int t = 0; t < 9; ++t)
            wreg[j][t] = s_w0[l * 18 + j * 9 + t];

    float* obase = out + (l * 4 + p) * 3136 + h * 56;
    #pragma unroll
    for (int i7 = 0; i7 < 7; ++i7) {
        const int n = b + i7 * 8;         // [0,56)
        float acc = 0.f;
        #pragma unroll
        for (int k = 0; k < 3; ++k) {
            float s = 0.f;
            #pragma unroll
            for (int j = 0; j < 2; ++j) {
                const float* rp = &s_t4[j][n];   // rp[d] = t4[.., n+d-2]
                s += wreg[j][0 + k] * rp[k + 0]; // i=0
                s += wreg[j][3 + k] * rp[k + 1]; // i=1
                s += wreg[j][6 + k] * rp[k + 2]; // i=2
            }
            const int m = n + k - 1;             // first-unfold position
            acc += ((unsigned)m < 56u) ? s : 0.f;
        }
        obase[n] = acc;
    }
}

extern "C" void kernel_launch(void* const* d_in, const int* in_sizes, int n_in,
                              void* d_out, int out_size, void* d_ws, size_t ws_size,
                              hipStream_t stream) {
    (void)in_sizes; (void)n_in; (void)out_size; (void)d_ws; (void)ws_size;
    const float* x  = (const float*)d_in[0];   // [1,128,56,56]
    const float* w0 = (const float*)d_in[1];   // [32,2,3,3]
    const float* w1 = (const float*)d_in[2];   // [4,64]
    float* out = (float*)d_out;                // [1,128,56,56]

    dim3 grid(56, 4);
    fused_shift_unfold_kernel<<<grid, 256, 0, stream>>>(x, w0, w1, out);
}